// Round 12
// baseline (823.349 us; speedup 1.0000x reference)
//
#include <hip/hip_runtime.h>
#include <hip/hip_bf16.h>

typedef __hip_bfloat16 bf16;
typedef __attribute__((ext_vector_type(8))) short v8s;   // 8 bf16 MFMA A/B frag
typedef __attribute__((ext_vector_type(4))) float v4f;   // MFMA C/D frag

#define NN 2048
#define EE 16384
#define LLAYERS 8
#define HIDD 256
#define ENCD 236
#define PED 20
#define BN_EPS 1e-5f
// 1/sqrt(32) * log2(e): QKV epilogue scales Q so scores land in log2 domain;
// attention then uses exp2f (raw v_exp_f32, no extra mul).
#define ATT_SCALE_L2E (0.17677669529663687f * 1.4426950408889634f)
#define KSPLIT 4

__device__ __forceinline__ float b2f(bf16 v){ return __bfloat162float(v); }
__device__ __forceinline__ float bs2f(unsigned short u){ return __uint_as_float(((unsigned)u) << 16); }
__device__ __forceinline__ unsigned short f2bs(float f){
  bf16 h = __float2bfloat16(f);
  union { bf16 b; unsigned short u; } cv; cv.b = h; return cv.u;
}
__device__ __forceinline__ float ld1f(const void* p, size_t i, int f){
  return f ? b2f(((const bf16*)p)[i]) : ((const float*)p)[i];
}

// ---------------- dtype + mask layout detector ----------------
__global__ void k_detect2(const unsigned int* __restrict__ xw,
                          const unsigned char* __restrict__ mk, int* __restrict__ flags){
  __shared__ int sh[256];
  int t = threadIdx.x;
  if (blockIdx.x == 0){
    int cnt = 0;
    for (int i = t; i < 8192; i += 256){
      unsigned b = (xw[i] >> 8) & 0xffu;
      unsigned v = b & 0x7fu;
      if (v == 0u || (v >= 0x30u && v <= 0x43u)) cnt++;
    }
    sh[t] = cnt; __syncthreads();
    for (int s = 128; s; s >>= 1){ if (t < s) sh[t] += sh[t+s]; __syncthreads(); }
    if (t == 0) flags[0] = (sh[0] > 6000) ? 1 : 0;
  } else {
    int acc = 0;
    for (int i = t; i < NN*6; i += 256){
      unsigned b = mk[i]; int m = i & 3;
      if ((m == 1 && b == 0x3Fu) || (m == 0 && b == 0x80u)) acc |= 4;
      if (b == 0x3Fu || b == 0x80u) acc |= 2;
      if (m != 0 && b != 0u) acc |= 1;
    }
    sh[t] = acc; __syncthreads();
    for (int s = 128; s; s >>= 1){ if (t < s) sh[t] |= sh[t+s]; __syncthreads(); }
    if (t == 0){
      int a = sh[0];
      flags[1] = (a & 4) ? 2 : (a & 2) ? 3 : (a & 1) ? 1 : 0;
    }
  }
}

// ---------------- weight transposes ----------------
__global__ void k_tw(const void* __restrict__ src, unsigned short* __restrict__ dst,
                     int K, int N, const int* __restrict__ dflag){
  __shared__ float tile[32][33];
  int n0 = blockIdx.x*32, k0 = blockIdx.y*32, b = blockIdx.z;
  int t = threadIdx.x, x = t & 31, y = t >> 5;
  int f = dflag[0];
  size_t so = (size_t)b*K*N, dofs = (size_t)b*N*K;
  #pragma unroll
  for (int i = 0; i < 4; i++){
    int k = k0 + y + 8*i;
    tile[y+8*i][x] = ld1f(src, so + (size_t)k*N + n0 + x, f);
  }
  __syncthreads();
  #pragma unroll
  for (int i = 0; i < 4; i++){
    int n = n0 + y + 8*i;
    dst[dofs + (size_t)n*K + k0 + x] = f2bs(tile[x][y+8*i]);
  }
}
// 17 batches of 256x256 from 3 sources (gine_mw x8, attn_outw x8, dec1w x1)
__global__ void k_tw3(const void* __restrict__ sA, const void* __restrict__ sB,
                      const void* __restrict__ sC, unsigned short* __restrict__ dst,
                      const int* __restrict__ dflag){
  __shared__ float tile[32][33];
  int z = blockIdx.z;
  const void* src = (z < 8) ? sA : (z < 16) ? sB : sC;
  int b = (z < 8) ? z : (z < 16) ? z - 8 : 0;
  int n0 = blockIdx.x*32, k0 = blockIdx.y*32;
  int t = threadIdx.x, x = t & 31, y = t >> 5;
  int f = dflag[0];
  size_t so = (size_t)b*65536, dofs = (size_t)z*65536;
  #pragma unroll
  for (int i = 0; i < 4; i++){
    int k = k0 + y + 8*i;
    tile[y+8*i][x] = ld1f(src, so + (size_t)k*256 + n0 + x, f);
  }
  __syncthreads();
  #pragma unroll
  for (int i = 0; i < 4; i++){
    int n = n0 + y + 8*i;
    dst[dofs + (size_t)n*256 + k0 + x] = f2bs(tile[x][y+8*i]);
  }
}

// ---------------- CSR build ----------------
__global__ void k_csr_count(const int* __restrict__ ei, int* __restrict__ counts){
  int e = blockIdx.x*256 + threadIdx.x;
  if (e < EE) atomicAdd(&counts[ei[EE + e]], 1);
}
__global__ void k_csr_scan(const int* __restrict__ counts, int* __restrict__ rowstart,
                           int* __restrict__ cursor){
  __shared__ int ts[256];
  int t = threadIdx.x, base = t*8;
  int loc[8]; int s = 0;
  #pragma unroll
  for (int i = 0; i < 8; i++){ loc[i] = s; s += counts[base + i]; }
  ts[t] = s; __syncthreads();
  for (int off = 1; off < 256; off <<= 1){
    int v = (t >= off) ? ts[t - off] : 0;
    __syncthreads();
    ts[t] += v;
    __syncthreads();
  }
  int excl = ts[t] - s;
  #pragma unroll
  for (int i = 0; i < 8; i++){
    int v = excl + loc[i];
    rowstart[base + i] = v; cursor[base + i] = v;
  }
  if (t == 255) rowstart[2048] = ts[255];
}
__global__ void k_csr_fill(const int* __restrict__ ei, const void* __restrict__ ea,
                           const int* __restrict__ dflag, int* __restrict__ cursor,
                           int* __restrict__ csr_src, float2* __restrict__ csr_a){
  int e = blockIdx.x*256 + threadIdx.x;
  if (e >= EE) return;
  int s = ei[e], d = ei[EE + e];
  int pos = atomicAdd(&cursor[d], 1);
  int f = dflag[0];
  csr_src[pos] = s;
  csr_a[pos] = make_float2(ld1f(ea, (size_t)e*2, f), ld1f(ea, (size_t)e*2 + 1, f));
}

// ---------------- encoder (also converts pe via spare threads) --------------
__global__ void k_encode(const void* __restrict__ x, const void* __restrict__ mval,
                         const void* __restrict__ mask, const int* __restrict__ flags,
                         const void* __restrict__ w, const void* __restrict__ b,
                         const void* __restrict__ pe,
                         float* __restrict__ out, float* __restrict__ pef){
  __shared__ float xr[16];
  int r = blockIdx.x, t = threadIdx.x;
  int f = flags[0];
  if (t < 9){
    float v = ld1f(x, (size_t)r*9 + t, f);
    if (t >= 3){
      int j = t - 3;
      size_t idx = (size_t)r*6 + j;
      int mf = flags[1];
      bool mm;
      if      (mf == 0) mm = ((const int*)mask)[idx] != 0;
      else if (mf == 1) mm = ((const unsigned char*)mask)[idx] != 0;
      else if (mf == 2) mm = ((const unsigned short*)mask)[idx] != 0;
      else              mm = ((const unsigned int*)mask)[idx] != 0;
      if (mm) v = ld1f(mval, j, f);
    }
    xr[t] = v;
  }
  __syncthreads();
  if (t < ENCD){
    float acc = ld1f(b, t, f);
    #pragma unroll
    for (int k = 0; k < 9; k++) acc = fmaf(xr[k], ld1f(w, (size_t)k*ENCD + t, f), acc);
    out[r*ENCD + t] = acc > 0.f ? acc : 0.01f*acc;
  } else {
    int j = t - ENCD;  // 0..19
    pef[(size_t)r*PED + j] = ld1f(pe, (size_t)r*PED + j, f);
  }
}
// merged encoder BN stats
__global__ void k_bn2x(const float* __restrict__ encb, const float* __restrict__ pef,
                       const void* __restrict__ eg, const void* __restrict__ eb,
                       const void* __restrict__ pg, const void* __restrict__ pb,
                       const int* __restrict__ dflag,
                       float* __restrict__ scE, float* __restrict__ shE,
                       float* __restrict__ scP, float* __restrict__ shP){
  int cb = blockIdx.x, t = threadIdx.x;
  const float* src; int ld, c; const void *g, *b; float *sc, *sh;
  if (cb < ENCD){ src = encb; ld = ENCD; c = cb; g = eg; b = eb; sc = scE; sh = shE; }
  else          { src = pef;  ld = PED;  c = cb - ENCD; g = pg; b = pb; sc = scP; sh = shP; }
  float s = 0.f, q = 0.f;
  for (int r = t; r < NN; r += 256){ float v = src[(size_t)r*ld + c]; s += v; q += v*v; }
  __shared__ float ss[256], qs[256];
  ss[t] = s; qs[t] = q; __syncthreads();
  for (int k = 128; k; k >>= 1){ if (t < k){ ss[t] += ss[t+k]; qs[t] += qs[t+k]; } __syncthreads(); }
  if (t == 0){
    int f = dflag[0];
    float mu  = ss[0] * (1.f/NN);
    float var = qs[0] * (1.f/NN) - mu*mu;
    float r1  = rsqrtf(var + BN_EPS);
    float scv = ld1f(g, c, f) * r1;
    sc[c] = scv; sh[c] = ld1f(b, c, f) - mu*scv;
  }
}
__global__ void k_concat(unsigned short* __restrict__ h, const float* __restrict__ encb,
                         const float* __restrict__ pef,
                         const float* __restrict__ scE, const float* __restrict__ shE,
                         const float* __restrict__ scP, const float* __restrict__ shP){
  int i = blockIdx.x*256 + threadIdx.x;
  int r = i >> 8, c = i & 255;
  float v;
  if (c < ENCD) v = encb[r*ENCD + c]*scE[c] + shE[c];
  else { int j = c - ENCD; v = pef[r*PED + j]*scP[j] + shP[j]; }
  h[i] = f2bs(v);
}

// ---------------- inline BN helpers ----------------
__device__ __forceinline__ void dualbn(const float* slab, int c, int f,
                                       const void* g1, size_t g1o,
                                       const void* g2, size_t g2o,
                                       const void* b2, size_t b2o,
                                       float& sc, float& sh){
  float mu  = slab[2*c] * (1.f/NN);
  float var = slab[2*c+1] * (1.f/NN) - mu*mu;
  float r1  = rsqrtf(var + BN_EPS);
  float gg  = ld1f(g1, g1o + c, f);
  float zv  = var * r1 * r1 * gg * gg;
  float r2  = rsqrtf(zv + BN_EPS);
  sc = r1 * gg * r2 * ld1f(g2, g2o + c, f);
  sh = ld1f(b2, b2o + c, f) - mu*sc;
}
__device__ __forceinline__ void singlebn(const float* slab, int c, int f,
                                         const void* g, size_t go,
                                         const void* b, size_t bo,
                                         float& sc, float& sh){
  float mu  = slab[2*c] * (1.f/NN);
  float var = slab[2*c+1] * (1.f/NN) - mu*mu;
  float r1  = rsqrtf(var + BN_EPS);
  sc = ld1f(g, go + c, f) * r1;
  sh = ld1f(b, bo + c, f) - mu*sc;
}

// ---------------- GINE gather (1-ahead CSR prefetch) ----------------
__device__ void dev_gather(const unsigned short* __restrict__ h0,
                           const float* __restrict__ t3, int hsrc,
                           const float* __restrict__ slabH,
                           const void* Hg1, size_t Hg1o, const void* Hg2, size_t Hg2o,
                           const void* Hb2, size_t Hb2o,
                           int dst, const int* __restrict__ rowstart,
                           const int* __restrict__ csr_src, const float2* __restrict__ csr_a,
                           const void* __restrict__ w, size_t woff,
                           const void* __restrict__ b, size_t boff, int f,
                           float* __restrict__ agg){
  int c = threadIdx.x;
  float sc = 1.f, sh = 0.f;
  if (hsrc) dualbn(slabH, c, f, Hg1, Hg1o, Hg2, Hg2o, Hb2, Hb2o, sc, sh);
  float w0 = ld1f(w, woff + c, f), w1 = ld1f(w, woff + HIDD + c, f);
  float bb = ld1f(b, boff + c, f);
  int beg = rowstart[dst], end = rowstart[dst + 1];
  float acc = 0.f;
  int sN = 0; float2 aN = make_float2(0.f, 0.f);
  if (beg < end){ sN = csr_src[beg]; aN = csr_a[beg]; }
  for (int i = beg; i < end; i++){
    int s = sN; float2 a = aN;
    if (i + 1 < end){ sN = csr_src[i + 1]; aN = csr_a[i + 1]; }
    float hv = hsrc ? t3[(size_t)s*HIDD + c]*sc + sh : bs2f(h0[(size_t)s*HIDD + c]);
    float m = hv + a.x*w0 + a.y*w1 + bb;
    acc += fmaxf(m, 0.f);
  }
  agg[(size_t)dst*HIDD + c] = acc;
}

// ---------------- MFMA GEMM device fn (software-pipelined K loop) -----------
// APATH: 0 = A from (h0 bf16 | t3 f32*BN); 1 = GINE: H + agg;
//        2 = attn K-split combine (Opart, lsum) — plain sums, not prefetched;
//        3 = dual single-BN(t1,t2); 4 = decoder triple-BN fold.
// RESMODE: 0 none; 1 += H; 2 += BN1(t1)+BN2(t2).
template<int ACT, int APATH, int RESMODE, int OUTBF, int STATS>
__device__ void dev_mgemm(char* sm, int bn, int bm,
    const unsigned short* __restrict__ Ab, const float* __restrict__ Af, int hsrc,
    const float* __restrict__ agg,
    const float* __restrict__ Opart, const float* __restrict__ lsum,
    const float* __restrict__ t1p, const float* __restrict__ t2p,
    const float* __restrict__ slabH,
    const void* Hg1, size_t Hg1o, const void* Hg2, size_t Hg2o,
    const void* Hb2, size_t Hb2o,
    const void* Pg, size_t Pgo, const void* Pb, size_t Pbo,
    const float* __restrict__ slab1,
    const void* g1, size_t g1o, const void* b1, size_t b1o,
    const float* __restrict__ slab2,
    const void* g2, size_t g2o, const void* b2, size_t b2o,
    const unsigned short* __restrict__ Wt,
    const void* __restrict__ bias, size_t boff,
    void* __restrict__ C, int N_, int K, int qcols, float qscale,
    float* __restrict__ stats, int f){
  unsigned short (*As)[40] = (unsigned short(*)[40])sm;
  unsigned short (*Bs)[40] = (unsigned short(*)[40])(sm + 5120);
  constexpr bool NEEDH = (APATH <= 1 || RESMODE == 1 || APATH == 4);
  constexpr size_t TB = 10240 + (NEEDH ? 2048 : 0);
  float* scH = (float*)(sm + 10240); float* shH = scH + 256;
  float* tc1 = (float*)(sm + TB);    float* th1 = tc1 + 256;
  float* tc2 = th1 + 256;            float* th2 = tc2 + 256;
  int tid = threadIdx.x, L = tid & 63, wv = tid >> 6;
  int wm = wv >> 1, wn = wv & 1;
  int quad = L >> 4, lo = L & 15;
  int srow = tid >> 2, sk = (tid & 3)*8;
  int arow = bm + srow;

  if (NEEDH && (hsrc || APATH == 4)){
    int c = tid;
    float s, h;
    dualbn(slabH, c, f, Hg1, Hg1o, Hg2, Hg2o, Hb2, Hb2o, s, h);
    if (APATH == 4){
      float mu  = slabH[2*c] * (1.f/NN);
      float var = slabH[2*c+1] * (1.f/NN) - mu*mu;
      float muh = mu*s + h, varh = var*s*s;
      float rp  = rsqrtf(varh + BN_EPS);
      float sp  = ld1f(Pg, Pgo + c, f) * rp;
      float hp  = ld1f(Pb, Pbo + c, f) - muh*sp;
      s = s*sp; h = h*sp + hp;
    }
    scH[c] = s; shH[c] = h;
  }
  if (APATH == 3 || RESMODE == 2){
    int c = tid;
    float s, h;
    singlebn(slab1, c, f, g1, g1o, b1, b1o, s, h); tc1[c] = s; th1[c] = h;
    singlebn(slab2, c, f, g2, g2o, b2, b2o, s, h); tc2[c] = s; th2[c] = h;
  }
  __syncthreads();

  // prefetch registers (raw data only; transforms happen at consume time)
  uint4 bP = {};
  uint4 aP = {};
  float4 fP0 = {}, fP1 = {}, fP2 = {}, fP3 = {};
  auto fetch_raw = [&](int c0){
    bP = *(const uint4*)(Wt + (size_t)(bn + srow)*K + c0);
    if (APATH == 0 || APATH == 4){
      if (APATH == 0 && !hsrc){
        aP = *(const uint4*)(Ab + (size_t)arow*K + c0);
      } else {
        fP0 = *(const float4*)(Af + (size_t)arow*K + c0);
        fP1 = *(const float4*)(Af + (size_t)arow*K + c0 + 4);
      }
    } else if (APATH == 1){
      if (!hsrc){
        aP = *(const uint4*)(Ab + (size_t)arow*K + c0);
      } else {
        fP0 = *(const float4*)(Af + (size_t)arow*K + c0);
        fP1 = *(const float4*)(Af + (size_t)arow*K + c0 + 4);
      }
      fP2 = *(const float4*)(agg + (size_t)arow*K + c0);
      fP3 = *(const float4*)(agg + (size_t)arow*K + c0 + 4);
    } else if (APATH == 3){
      fP0 = *(const float4*)(t1p + (size_t)arow*HIDD + c0);
      fP1 = *(const float4*)(t1p + (size_t)arow*HIDD + c0 + 4);
      fP2 = *(const float4*)(t2p + (size_t)arow*HIDD + c0);
      fP3 = *(const float4*)(t2p + (size_t)arow*HIDD + c0 + 4);
    }
  };
  auto make_aval = [&](int c0)->uint4 {
    if (APATH == 0 && !hsrc) return aP;
    if (APATH == 0 || APATH == 4){
      unsigned short us8[8];
      float fa[8] = {fP0.x,fP0.y,fP0.z,fP0.w,fP1.x,fP1.y,fP1.z,fP1.w};
      #pragma unroll
      for (int j = 0; j < 8; j++){
        int c = c0 + j;
        us8[j] = f2bs(fa[j]*scH[c] + shH[c]);
      }
      return *(const uint4*)us8;
    }
    if (APATH == 1){
      unsigned short us8[8];
      float ga[8] = {fP2.x,fP2.y,fP2.z,fP2.w,fP3.x,fP3.y,fP3.z,fP3.w};
      if (!hsrc){
        unsigned parts[4] = {aP.x, aP.y, aP.z, aP.w};
        #pragma unroll
        for (int p = 0; p < 4; p++){
          us8[2*p]   = f2bs(bs2f((unsigned short)(parts[p] & 0xffffu)) + ga[2*p]);
          us8[2*p+1] = f2bs(bs2f((unsigned short)(parts[p] >> 16))     + ga[2*p+1]);
        }
      } else {
        float fa[8] = {fP0.x,fP0.y,fP0.z,fP0.w,fP1.x,fP1.y,fP1.z,fP1.w};
        #pragma unroll
        for (int j = 0; j < 8; j++){
          int c = c0 + j;
          us8[j] = f2bs(fa[j]*scH[c] + shH[c] + ga[j]);
        }
      }
      return *(const uint4*)us8;
    }
    if (APATH == 2){
      int hd = c0 >> 5, d0 = c0 & 31;
      size_t mlb = ((size_t)arow*8 + hd)*KSPLIT;
      float inv = 1.f / (lsum[mlb] + lsum[mlb+1] + lsum[mlb+2] + lsum[mlb+3]);
      const float* Op = Opart + mlb*32 + d0;
      unsigned short us8[8];
      #pragma unroll
      for (int j = 0; j < 8; j++){
        float v = (Op[j] + Op[32+j] + Op[64+j] + Op[96+j])*inv;
        us8[j] = f2bs(v);
      }
      return *(const uint4*)us8;
    }
    // APATH == 3
    unsigned short us8[8];
    float fa[8] = {fP0.x,fP0.y,fP0.z,fP0.w,fP1.x,fP1.y,fP1.z,fP1.w};
    float fb[8] = {fP2.x,fP2.y,fP2.z,fP2.w,fP3.x,fP3.y,fP3.z,fP3.w};
    #pragma unroll
    for (int j = 0; j < 8; j++){
      int c = c0 + j;
      us8[j] = f2bs(fa[j]*tc1[c] + th1[c] + fb[j]*tc2[c] + th2[c]);
    }
    return *(const uint4*)us8;
  };

  v4f acc[2][2];
  #pragma unroll
  for (int i = 0; i < 2; i++)
    #pragma unroll
    for (int j = 0; j < 2; j++) acc[i][j] = (v4f){0.f,0.f,0.f,0.f};

  fetch_raw(sk);
  for (int kk = 0; kk < K; kk += 32){
    int c0 = kk + sk;
    uint4 aval = make_aval(c0);
    uint4 bval = bP;
    __syncthreads();
    *(uint4*)&As[srow][sk] = aval;
    *(uint4*)&Bs[srow][sk] = bval;
    __syncthreads();
    if (kk + 32 < K) fetch_raw(kk + 32 + sk);   // overlaps the MFMA section
    v8s af[2], bfr[2];
    af[0]  = *(const v8s*)&As[wm*32 + lo][quad*8];
    af[1]  = *(const v8s*)&As[wm*32 + 16 + lo][quad*8];
    bfr[0] = *(const v8s*)&Bs[wn*32 + lo][quad*8];
    bfr[1] = *(const v8s*)&Bs[wn*32 + 16 + lo][quad*8];
    #pragma unroll
    for (int mi = 0; mi < 2; mi++)
      #pragma unroll
      for (int nj = 0; nj < 2; nj++)
        acc[mi][nj] = __builtin_amdgcn_mfma_f32_16x16x32_bf16(af[mi], bfr[nj], acc[mi][nj], 0, 0, 0);
  }

  float ssum[2] = {0.f, 0.f}, ssq[2] = {0.f, 0.f};
  #pragma unroll
  for (int mi = 0; mi < 2; mi++){
    #pragma unroll
    for (int nj = 0; nj < 2; nj++){
      int col = bn + wn*32 + nj*16 + lo;
      float bv = ld1f(bias, boff + col, f);
      #pragma unroll
      for (int r = 0; r < 4; r++){
        int row = bm + wm*32 + mi*16 + quad*4 + r;
        float t = acc[mi][nj][r] + bv;
        if (ACT == 1) t = fmaxf(t, 0.f);
        if (ACT == 2) t = t > 0.f ? t : 0.01f*t;
        if (qcols && col < qcols) t *= qscale;
        if (RESMODE == 1)
          t += hsrc ? (Af[(size_t)row*N_ + col]*scH[col] + shH[col])
                    : bs2f(Ab[(size_t)row*N_ + col]);
        if (RESMODE == 2)
          t += t1p[(size_t)row*HIDD + col]*tc1[col] + th1[col]
             + t2p[(size_t)row*HIDD + col]*tc2[col] + th2[col];
        if (STATS){ ssum[nj] += t; ssq[nj] += t*t; }
        if (OUTBF) ((unsigned short*)C)[(size_t)row*N_ + col] = f2bs(t);
        else       ((float*)C)[(size_t)row*N_ + col] = t;
      }
    }
  }
  if (STATS){
    #pragma unroll
    for (int nj = 0; nj < 2; nj++){
      float s = ssum[nj], q = ssq[nj];
      s += __shfl_xor(s, 16, 64); s += __shfl_xor(s, 32, 64);
      q += __shfl_xor(q, 16, 64); q += __shfl_xor(q, 32, 64);
      if (quad == 0){
        int col = bn + wn*32 + nj*16 + lo;
        atomicAdd(&stats[2*col],   s);
        atomicAdd(&stats[2*col+1], q);
      }
    }
  }
}

// ---------------- MFMA flash attention: 512 threads, 128 q-rows/block -------
// no-max softmax in log2 domain; K/V staged with depth-2 register prefetch so
// global-load latency overlaps the QK/exp/PV compute section.
__launch_bounds__(512)
__global__ void k_d2(const unsigned short* __restrict__ qkv,
                     float* __restrict__ Opart, float* __restrict__ lsum){
  __shared__ unsigned short Ks[64][40];
  __shared__ unsigned short Vt[32][66];
  __shared__ unsigned short Ps[8][16][68];
  int b = blockIdx.x;
  int qt = b & 15, hd = (b >> 4) & 7, ks = b >> 7;
  int q0 = qt*128;
  int tid = threadIdx.x, L = tid & 63, wv = tid >> 6;   // wv 0..7
  int quad = L >> 4, lo = L & 15;
  int skey = tid >> 3, sd = (tid & 7)*4;

  v8s qf = *(const v8s*)(qkv + (size_t)(q0 + 16*wv + lo)*768 + hd*32 + quad*8);
  v4f o0 = (v4f){0.f,0.f,0.f,0.f}, o1 = (v4f){0.f,0.f,0.f,0.f};
  float lrow[4] = {0.f, 0.f, 0.f, 0.f};

  int kbeg = ks * (NN/KSPLIT), kend = kbeg + NN/KSPLIT;
  const unsigned short* kp0 = qkv + (size_t)(kbeg + skey)*768 + 256 + hd*32 + sd;
  uint2 kraw = *(const uint2*)kp0;
  uint2 vraw = *(const uint2*)(kp0 + 256);
  for (int kt = kbeg; kt < kend; kt += 64){
    __syncthreads();                    // prev iter's Ks/Vt readers done
    *(uint2*)&Ks[skey][sd] = kraw;
    {
      unsigned short vs[4]; *(uint2*)vs = vraw;
      #pragma unroll
      for (int j = 0; j < 4; j++) Vt[sd + j][skey] = vs[j];
    }
    __syncthreads();
    if (kt + 64 < kend){                // prefetch next K/V tile
      const unsigned short* kp = qkv + (size_t)(kt + 64 + skey)*768 + 256 + hd*32 + sd;
      kraw = *(const uint2*)kp;
      vraw = *(const uint2*)(kp + 256);
    }
    v4f s[4];
    #pragma unroll
    for (int sub = 0; sub < 4; sub++){
      v8s kf = *(const v8s*)&Ks[sub*16 + lo][quad*8];
      s[sub] = __builtin_amdgcn_mfma_f32_16x16x32_bf16(qf, kf, (v4f){0.f,0.f,0.f,0.f}, 0, 0, 0);
    }
    #pragma unroll
    for (int r = 0; r < 4; r++){
      #pragma unroll
      for (int sub = 0; sub < 4; sub++){
        float p = exp2f(s[sub][r]);
        Ps[wv][quad*4 + r][sub*16 + lo] = f2bs(p);
        lrow[r] += p;
      }
    }
    // Ps is wave-private: no block barrier needed before PV
    #pragma unroll
    for (int kc = 0; kc < 2; kc++){
      v8s pf  = *(const v8s*)&Ps[wv][lo][kc*32 + quad*8];
      v8s v0f = *(const v8s*)&Vt[lo][kc*32 + quad*8];
      v8s v1f = *(const v8s*)&Vt[16 + lo][kc*32 + quad*8];
      o0 = __builtin_amdgcn_mfma_f32_16x16x32_bf16(pf, v0f, o0, 0, 0, 0);
      o1 = __builtin_amdgcn_mfma_f32_16x16x32_bf16(pf, v1f, o1, 0, 0, 0);
    }
  }
  #pragma unroll
  for (int r = 0; r < 4; r++){
    float v = lrow[r];
    #pragma unroll
    for (int off = 1; off < 16; off <<= 1) v += __shfl_xor(v, off, 64);
    lrow[r] = v;
  }
  #pragma unroll
  for (int r = 0; r < 4; r++){
    int row = q0 + 16*wv + quad*4 + r;
    size_t base = (((size_t)row*8 + hd)*KSPLIT + ks)*32;
    Opart[base + lo]      = o0[r];
    Opart[base + 16 + lo] = o1[r];
    if (lo == 0) lsum[((size_t)row*8 + hd)*KSPLIT + ks] = lrow[r];
  }
}

// ---------------- fat dispatch 1: QKV GEMM (384) + gather (2048) ----------
__launch_bounds__(256)
__global__ void k_d1(const unsigned short* __restrict__ h0, const float* __restrict__ t3,
                     int hsrc, const float* __restrict__ slabH,
                     const void* Hg1, size_t Hg1o, const void* Hg2, size_t Hg2o,
                     const void* Hb2, size_t Hb2o,
                     const unsigned short* __restrict__ qkw,
                     const void* qb, size_t qbo, unsigned short* __restrict__ qkvb,
                     const int* __restrict__ rowstart, const int* __restrict__ csr_src,
                     const float2* __restrict__ csr_a,
                     const void* gw, size_t gwo, const void* gb, size_t gbo,
                     float* __restrict__ agg, const int* __restrict__ dflagp){
  __shared__ char sm[12288];
  int f = dflagp[0];
  int bx = blockIdx.x;
  if (bx < 384){
    dev_mgemm<0,0,0,1,0>(sm, (bx % 12)*64, (bx / 12)*64, h0, t3, hsrc,
        nullptr, nullptr, nullptr, nullptr, nullptr,
        slabH, Hg1, Hg1o, Hg2, Hg2o, Hb2, Hb2o, nullptr, 0, nullptr, 0,
        nullptr, nullptr, 0, nullptr, 0, nullptr, nullptr, 0, nullptr, 0,
        qkw, qb, qbo, qkvb, 768, 256, 256, ATT_SCALE_L2E, nullptr, f);
  } else {
    dev_gather(h0, t3, hsrc, slabH, Hg1, Hg1o, Hg2, Hg2o, Hb2, Hb2o,
               bx - 384, rowstart, csr_src, csr_a, gw, gwo, gb, gbo, f, agg);
  }
}

// ---------------- fat dispatch 3: GINE GEMM (128) + attn-out GEMM (128) ----
// NOTE: t2 must NOT alias agg — the gine branch reads agg while the attnout
// branch writes t2 concurrently (this race caused the r11 failure).
__launch_bounds__(256)
__global__ void k_g3(const unsigned short* __restrict__ h0, const float* __restrict__ t3,
                     int hsrc, const float* __restrict__ slabH,
                     const void* Hg1, size_t Hg1o, const void* Hg2, size_t Hg2o,
                     const void* Hb2, size_t Hb2o,
                     const float* __restrict__ agg,
                     const unsigned short* __restrict__ gmw,
                     const void* gmb, size_t gmbo,
                     float* __restrict__ t1, float* __restrict__ stats1,
                     const float* __restrict__ Opart, const float* __restrict__ lsum,
                     const unsigned short* __restrict__ aow,
                     const void* aob, size_t aobo,
                     float* __restrict__ t2, float* __restrict__ stats2,
                     const int* __restrict__ dflagp){
  __shared__ char sm[12288];
  int f = dflagp[0];
  int bx = blockIdx.x;
  if (bx < 128){
    dev_mgemm<2,1,1,0,1>(sm, (bx & 3)*64, (bx >> 2)*64, h0, t3, hsrc,
        agg, nullptr, nullptr, nullptr, nullptr,
        slabH, Hg1, Hg1o, Hg2, Hg2o, Hb2, Hb2o, nullptr, 0, nullptr, 0,
        nullptr, nullptr, 0, nullptr, 0, nullptr, nullptr, 0, nullptr, 0,
        gmw, gmb, gmbo, t1, 256, 256, 0, 1.f, stats1, f);
  } else {
    int bb = bx - 128;
    dev_mgemm<0,2,1,0,1>(sm, (bb & 3)*64, (bb >> 2)*64, h0, t3, hsrc,
        nullptr, Opart, lsum, nullptr, nullptr,
        slabH, Hg1, Hg1o, Hg2, Hg2o, Hb2, Hb2o, nullptr, 0, nullptr, 0,
        nullptr, nullptr, 0, nullptr, 0, nullptr, nullptr, 0, nullptr, 0,
        aow, aob, aobo, t2, 256, 256, 0, 1.f, stats2, f);
  }
}

// ---------------- mlp1 GEMM ----------------
__launch_bounds__(256)
__global__ void k_g4(const float* __restrict__ t1, const float* __restrict__ t2,
                     const float* __restrict__ slab1,
                     const void* g1, size_t g1o, const void* b1, size_t b1o,
                     const float* __restrict__ slab2,
                     const void* g2, size_t g2o, const void* b2, size_t b2o,
                     const unsigned short* __restrict__ m1w,
                     const void* m1b, size_t m1bo,
                     unsigned short* __restrict__ u, const int* __restrict__ dflagp){
  __shared__ char sm[14336];
  dev_mgemm<1,3,0,1,0>(sm, blockIdx.x*64, blockIdx.y*64, nullptr, nullptr, 0,
      nullptr, nullptr, nullptr, t1, t2,
      nullptr, nullptr, 0, nullptr, 0, nullptr, 0, nullptr, 0, nullptr, 0,
      slab1, g1, g1o, b1, b1o, slab2, g2, g2o, b2, b2o,
      m1w, m1b, m1bo, u, 512, 256, 0, 1.f, nullptr, dflagp[0]);
}

// ---------------- mlp2 GEMM ----------------
__launch_bounds__(256)
__global__ void k_g5(const unsigned short* __restrict__ u,
                     const float* __restrict__ t1, const float* __restrict__ t2,
                     const float* __restrict__ slab1,
                     const void* g1, size_t g1o, const void* b1, size_t b1o,
                     const float* __restrict__ slab2,
                     const void* g2, size_t g2o, const void* b2, size_t b2o,
                     const unsigned short* __restrict__ m2w,
                     const void* m2b, size_t m2bo,
                     float* __restrict__ t3, float* __restrict__ stats3,
                     const int* __restrict__ dflagp){
  __shared__ char sm[14336];
  dev_mgemm<0,0,2,0,1>(sm, blockIdx.x*64, blockIdx.y*64, u, nullptr, 0,
      nullptr, nullptr, nullptr, t1, t2,
      nullptr, nullptr, 0, nullptr, 0, nullptr, 0, nullptr, 0, nullptr, 0,
      slab1, g1, g1o, b1, b1o, slab2, g2, g2o, b2, b2o,
      m2w, m2b, m2bo, t3, 256, 512, 0, 1.f, stats3, dflagp[0]);
}

// ---------------- decoder stage 1 GEMM ----------------
__launch_bounds__(256)
__global__ void k_gdec(const float* __restrict__ t3, const float* __restrict__ slabH,
                       const void* Hg1, size_t Hg1o, const void* Hg2, size_t Hg2o,
                       const void* Hb2, size_t Hb2o,
                       const void* Pg, const void* Pb,
                       const unsigned short* __restrict__ d1w,
                       const void* d1bv, unsigned short* __restrict__ d1b,
                       const int* __restrict__ dflagp){
  __shared__ char sm[12288];
  dev_mgemm<2,4,0,1,0>(sm, blockIdx.x*64, blockIdx.y*64, nullptr, t3, 1,
      nullptr, nullptr, nullptr, nullptr, nullptr,
      slabH, Hg1, Hg1o, Hg2, Hg2o, Hb2, Hb2o, Pg, 0, Pb, 0,
      nullptr, nullptr, 0, nullptr, 0, nullptr, nullptr, 0, nullptr, 0,
      d1w, d1bv, 0, d1b, 256, 256, 0, 1.f, nullptr, dflagp[0]);
}

// ---------------- decoder stage 2 ----------------
__global__ void k_dec2(const unsigned short* __restrict__ d1, const void* __restrict__ w,
                       const void* __restrict__ b, const int* __restrict__ dflag,
                       void* __restrict__ out){
  int r = blockIdx.x, t = threadIdx.x;
  int f = dflag[0];
  float a = bs2f(d1[(size_t)r*HIDD + t]);
  float p[6];
  #pragma unroll
  for (int n = 0; n < 6; n++) p[n] = a * ld1f(w, (size_t)t*6 + n, f);
  #pragma unroll
  for (int off = 32; off >= 1; off >>= 1)
    #pragma unroll
    for (int n = 0; n < 6; n++) p[n] += __shfl_down(p[n], off, 64);
  __shared__ float red[4][6];
  int wvv = t >> 6, ln = t & 63;
  if (ln == 0)
    #pragma unroll
    for (int n = 0; n < 6; n++) red[wvv][n] = p[n];
  __syncthreads();
  if (t < 6){
    float s = red[0][t] + red[1][t] + red[2][t] + red[3][t] + ld1f(b, t, f);
    if (f) ((bf16*)out)[r*6 + t] = __float2bfloat16(s);
    else   ((float*)out)[r*6 + t] = s;
  }
}

extern "C" void kernel_launch(void* const* d_in, const int* in_sizes, int n_in,
                              void* d_out, int out_size, void* d_ws, size_t ws_size,
                              hipStream_t stream){
  const void* x          = d_in[0];
  const void* pe         = d_in[1];
  const void* edge_attr  = d_in[2];
  const void* mask_value = d_in[3];
  const void* enc_w = d_in[4];  const void* enc_b = d_in[5];
  const void* in_g  = d_in[6];  const void* in_b  = d_in[7];
  const void* pe_g  = d_in[8];  const void* pe_b  = d_in[9];
  const void* gine_ew = d_in[10]; const void* gine_eb = d_in[11];
  const void* gine_mw = d_in[12]; const void* gine_mb = d_in[13];
  const void* attn_inw  = d_in[14]; const void* attn_inb  = d_in[15];
  const void* attn_outw = d_in[16]; const void* attn_outb = d_in[17];
  const void* mlp1w = d_in[18]; const void* mlp1b = d_in[19];
  const void* mlp2w = d_in[20]; const void* mlp2b = d_in[21];
  const void* n1g = d_in[22]; const void* n1b = d_in[23];
  const void* n2g = d_in[24]; const void* n2b = d_in[25];
  const void* n3g = d_in[26]; const void* n3b = d_in[27];
  const void* obn_g = d_in[28]; const void* obn_b = d_in[29];
  const void* pd_g  = d_in[30]; const void* pd_b  = d_in[31];
  const void* dec1w = d_in[32]; const void* dec1b = d_in[33];
  const void* dec2w = d_in[34]; const void* dec2b = d_in[35];
  const int*  edge_index = (const int*)d_in[36];
  const void* mask = d_in[37];
  (void)in_sizes; (void)n_in; (void)out_size; (void)ws_size;

  char* cur = (char*)d_ws;
  auto alloc = [&](size_t bytes)->char*{
    char* p = cur; cur += (bytes + 63) & ~(size_t)63; return p;
  };
  int*   flags = (int*)alloc(64);
  int*   dflag = flags;
  float* scE = (float*)alloc(ENCD*4); float* shE = (float*)alloc(ENCD*4);
  float* scP = (float*)alloc(PED*4);  float* shP = (float*)alloc(PED*4);
  int*   counts = (int*)alloc(2048*4);
  float* stats1 = (float*)alloc((size_t)LLAYERS*512*4);
  float* stats2 = (float*)alloc((size_t)LLAYERS*512*4);
  float* stats3 = (float*)alloc((size_t)LLAYERS*512*4);
  size_t zero_bytes = 2048*4 + 3*(size_t)LLAYERS*512*4;
  int*    rowstart = (int*)alloc(2052*4);
  int*    cursor   = (int*)alloc(2048*4);
  int*    csr_src  = (int*)alloc((size_t)EE*4);
  float2* csr_a    = (float2*)alloc((size_t)EE*8);
  unsigned short* h    = (unsigned short*)alloc((size_t)NN*HIDD*2);   // layer-0 only
  float*          t1   = (float*)alloc((size_t)NN*HIDD*4);
  float*          agg  = (float*)alloc((size_t)NN*HIDD*4);
  float*          t2   = (float*)alloc((size_t)NN*HIDD*4);   // DEDICATED (no agg alias!)
  float*          t3   = (float*)alloc((size_t)NN*HIDD*4);
  unsigned short* qkvb = (unsigned short*)alloc((size_t)NN*768*2);    // alias u, encb+pef
  float*          Opart= (float*)alloc((size_t)NN*8*KSPLIT*32*4);     // 8 MB; alias d1b
  float*          lsum = (float*)alloc((size_t)NN*8*KSPLIT*4);
  unsigned short* sqw  = (unsigned short*)alloc((size_t)17*65536*2);
  unsigned short* ainw_t = (unsigned short*)alloc((size_t)8*768*256*2);
  unsigned short* m1w_t  = (unsigned short*)alloc((size_t)8*512*256*2);
  unsigned short* m2w_t  = (unsigned short*)alloc((size_t)8*256*512*2);
  unsigned short* gmw_t   = sqw;
  unsigned short* aoutw_t = sqw + (size_t)8*65536;
  unsigned short* d1w_t   = sqw + (size_t)16*65536;
  unsigned short* u    = qkvb;
  float*          encb = (float*)qkvb;
  float*          pef  = (float*)qkvb + (size_t)NN*ENCD;
  unsigned short* d1b  = (unsigned short*)Opart;

  // ---- detection, CSR, transposes, encoder ----
  k_detect2<<<2, 256, 0, stream>>>((const unsigned int*)x, (const unsigned char*)mask, flags);
  hipMemsetAsync(counts, 0, zero_bytes, stream);
  k_csr_count<<<EE/256, 256, 0, stream>>>(edge_index, counts);
  k_csr_scan<<<1, 256, 0, stream>>>(counts, rowstart, cursor);
  k_csr_fill<<<EE/256, 256, 0, stream>>>(edge_index, edge_attr, dflag, cursor, csr_src, csr_a);
  k_tw3<<<dim3(8, 8, 17), 256, 0, stream>>>(gine_mw, attn_outw, dec1w, sqw, dflag);
  k_tw<<<dim3(24, 8, 8), 256, 0, stream>>>(attn_inw, ainw_t, 256, 768, dflag);
  k_tw<<<dim3(16, 8, 8), 256, 0, stream>>>(mlp1w,    m1w_t,  256, 512, dflag);
  k_tw<<<dim3(8, 16, 8), 256, 0, stream>>>(mlp2w,    m2w_t,  512, 256, dflag);
  k_encode<<<NN, 256, 0, stream>>>(x, mask_value, mask, flags, enc_w, enc_b, pe, encb, pef);
  k_bn2x<<<256, 256, 0, stream>>>(encb, pef, in_g, in_b, pe_g, pe_b, dflag, scE, shE, scP, shP);
  k_concat<<<NN*HIDD/256, 256, 0, stream>>>(h, encb, pef, scE, shE, scP, shP);

  for (int l = 0; l < LLAYERS; l++){
    int hs = (l > 0);
    const float* slH = stats3 + (size_t)(hs ? (l-1) : 0)*512;
    size_t o3 = (size_t)(hs ? (l-1) : 0)*256;
    k_d1<<<2432, 256, 0, stream>>>(h, t3, hs, slH, n3g, o3, obn_g, o3, obn_b, o3,
        ainw_t + (size_t)l*196608, attn_inb, (size_t)l*768, qkvb,
        rowstart, csr_src, csr_a,
        gine_ew, (size_t)l*2*HIDD, gine_eb, (size_t)l*HIDD, agg, dflag);
    k_d2<<<512, 512, 0, stream>>>(qkvb, Opart, lsum);
    k_g3<<<256, 256, 0, stream>>>(h, t3, hs, slH, n3g, o3, obn_g, o3, obn_b, o3,
        agg, gmw_t + (size_t)l*65536, gine_mb, (size_t)l*256, t1, stats1 + (size_t)l*512,
        Opart, lsum, aoutw_t + (size_t)l*65536, attn_outb, (size_t)l*256,
        t2, stats2 + (size_t)l*512, dflag);
    k_g4<<<dim3(8,32), 256, 0, stream>>>(t1, t2,
        stats1 + (size_t)l*512, n1g, (size_t)l*256, n1b, (size_t)l*256,
        stats2 + (size_t)l*512, n2g, (size_t)l*256, n2b, (size_t)l*256,
        m1w_t + (size_t)l*131072, mlp1b, (size_t)l*512, u, dflag);
    k_g5<<<dim3(4,32), 256, 0, stream>>>(u, t1, t2,
        stats1 + (size_t)l*512, n1g, (size_t)l*256, n1b, (size_t)l*256,
        stats2 + (size_t)l*512, n2g, (size_t)l*256, n2b, (size_t)l*256,
        m2w_t + (size_t)l*131072, mlp2b, (size_t)l*256, t3, stats3 + (size_t)l*512, dflag);
  }

  // ---- decoder ----
  k_gdec<<<dim3(4,32), 256, 0, stream>>>(t3, stats3 + (size_t)7*512,
      n3g, (size_t)7*256, obn_g, (size_t)7*256, obn_b, (size_t)7*256,
      pd_g, pd_b, d1w_t, dec1b, d1b, dflag);
  k_dec2<<<NN, 256, 0, stream>>>(d1b, dec2w, dec2b, dflag, d_out);
}

// Round 13
// 794.417 us; speedup vs baseline: 1.0364x; 1.0364x over previous
//
#include <hip/hip_runtime.h>
#include <hip/hip_bf16.h>

typedef __hip_bfloat16 bf16;
typedef __attribute__((ext_vector_type(8))) short v8s;   // 8 bf16 MFMA A/B frag
typedef __attribute__((ext_vector_type(4))) float v4f;   // MFMA C/D frag

#define NN 2048
#define EE 16384
#define LLAYERS 8
#define HIDD 256
#define ENCD 236
#define PED 20
#define BN_EPS 1e-5f
// 1/sqrt(32) * log2(e): QKV epilogue scales Q so scores land in log2 domain;
// attention then uses exp2f (raw v_exp_f32, no extra mul).
#define ATT_SCALE_L2E (0.17677669529663687f * 1.4426950408889634f)
#define KSPLIT 4

__device__ __forceinline__ float b2f(bf16 v){ return __bfloat162float(v); }
__device__ __forceinline__ float bs2f(unsigned short u){ return __uint_as_float(((unsigned)u) << 16); }
__device__ __forceinline__ unsigned short f2bs(float f){
  bf16 h = __float2bfloat16(f);
  union { bf16 b; unsigned short u; } cv; cv.b = h; return cv.u;
}
__device__ __forceinline__ float ld1f(const void* p, size_t i, int f){
  return f ? b2f(((const bf16*)p)[i]) : ((const float*)p)[i];
}

// ---------------- dtype + mask layout detector ----------------
__global__ void k_detect2(const unsigned int* __restrict__ xw,
                          const unsigned char* __restrict__ mk, int* __restrict__ flags){
  __shared__ int sh[256];
  int t = threadIdx.x;
  if (blockIdx.x == 0){
    int cnt = 0;
    for (int i = t; i < 8192; i += 256){
      unsigned b = (xw[i] >> 8) & 0xffu;
      unsigned v = b & 0x7fu;
      if (v == 0u || (v >= 0x30u && v <= 0x43u)) cnt++;
    }
    sh[t] = cnt; __syncthreads();
    for (int s = 128; s; s >>= 1){ if (t < s) sh[t] += sh[t+s]; __syncthreads(); }
    if (t == 0) flags[0] = (sh[0] > 6000) ? 1 : 0;
  } else {
    int acc = 0;
    for (int i = t; i < NN*6; i += 256){
      unsigned b = mk[i]; int m = i & 3;
      if ((m == 1 && b == 0x3Fu) || (m == 0 && b == 0x80u)) acc |= 4;
      if (b == 0x3Fu || b == 0x80u) acc |= 2;
      if (m != 0 && b != 0u) acc |= 1;
    }
    sh[t] = acc; __syncthreads();
    for (int s = 128; s; s >>= 1){ if (t < s) sh[t] |= sh[t+s]; __syncthreads(); }
    if (t == 0){
      int a = sh[0];
      flags[1] = (a & 4) ? 2 : (a & 2) ? 3 : (a & 1) ? 1 : 0;
    }
  }
}

// ---------------- weight transposes ----------------
__global__ void k_tw(const void* __restrict__ src, unsigned short* __restrict__ dst,
                     int K, int N, const int* __restrict__ dflag){
  __shared__ float tile[32][33];
  int n0 = blockIdx.x*32, k0 = blockIdx.y*32, b = blockIdx.z;
  int t = threadIdx.x, x = t & 31, y = t >> 5;
  int f = dflag[0];
  size_t so = (size_t)b*K*N, dofs = (size_t)b*N*K;
  #pragma unroll
  for (int i = 0; i < 4; i++){
    int k = k0 + y + 8*i;
    tile[y+8*i][x] = ld1f(src, so + (size_t)k*N + n0 + x, f);
  }
  __syncthreads();
  #pragma unroll
  for (int i = 0; i < 4; i++){
    int n = n0 + y + 8*i;
    dst[dofs + (size_t)n*K + k0 + x] = f2bs(tile[x][y+8*i]);
  }
}
// 17 batches of 256x256 from 3 sources (gine_mw x8, attn_outw x8, dec1w x1)
__global__ void k_tw3(const void* __restrict__ sA, const void* __restrict__ sB,
                      const void* __restrict__ sC, unsigned short* __restrict__ dst,
                      const int* __restrict__ dflag){
  __shared__ float tile[32][33];
  int z = blockIdx.z;
  const void* src = (z < 8) ? sA : (z < 16) ? sB : sC;
  int b = (z < 8) ? z : (z < 16) ? z - 8 : 0;
  int n0 = blockIdx.x*32, k0 = blockIdx.y*32;
  int t = threadIdx.x, x = t & 31, y = t >> 5;
  int f = dflag[0];
  size_t so = (size_t)b*65536, dofs = (size_t)z*65536;
  #pragma unroll
  for (int i = 0; i < 4; i++){
    int k = k0 + y + 8*i;
    tile[y+8*i][x] = ld1f(src, so + (size_t)k*256 + n0 + x, f);
  }
  __syncthreads();
  #pragma unroll
  for (int i = 0; i < 4; i++){
    int n = n0 + y + 8*i;
    dst[dofs + (size_t)n*256 + k0 + x] = f2bs(tile[x][y+8*i]);
  }
}

// ---------------- CSR build ----------------
__global__ void k_csr_count(const int* __restrict__ ei, int* __restrict__ counts){
  int e = blockIdx.x*256 + threadIdx.x;
  if (e < EE) atomicAdd(&counts[ei[EE + e]], 1);
}
__global__ void k_csr_scan(const int* __restrict__ counts, int* __restrict__ rowstart,
                           int* __restrict__ cursor){
  __shared__ int ts[256];
  int t = threadIdx.x, base = t*8;
  int loc[8]; int s = 0;
  #pragma unroll
  for (int i = 0; i < 8; i++){ loc[i] = s; s += counts[base + i]; }
  ts[t] = s; __syncthreads();
  for (int off = 1; off < 256; off <<= 1){
    int v = (t >= off) ? ts[t - off] : 0;
    __syncthreads();
    ts[t] += v;
    __syncthreads();
  }
  int excl = ts[t] - s;
  #pragma unroll
  for (int i = 0; i < 8; i++){
    int v = excl + loc[i];
    rowstart[base + i] = v; cursor[base + i] = v;
  }
  if (t == 255) rowstart[2048] = ts[255];
}
__global__ void k_csr_fill(const int* __restrict__ ei, const void* __restrict__ ea,
                           const int* __restrict__ dflag, int* __restrict__ cursor,
                           int* __restrict__ csr_src, float2* __restrict__ csr_a){
  int e = blockIdx.x*256 + threadIdx.x;
  if (e >= EE) return;
  int s = ei[e], d = ei[EE + e];
  int pos = atomicAdd(&cursor[d], 1);
  int f = dflag[0];
  csr_src[pos] = s;
  csr_a[pos] = make_float2(ld1f(ea, (size_t)e*2, f), ld1f(ea, (size_t)e*2 + 1, f));
}

// ---------------- encoder (also converts pe via spare threads) --------------
__global__ void k_encode(const void* __restrict__ x, const void* __restrict__ mval,
                         const void* __restrict__ mask, const int* __restrict__ flags,
                         const void* __restrict__ w, const void* __restrict__ b,
                         const void* __restrict__ pe,
                         float* __restrict__ out, float* __restrict__ pef){
  __shared__ float xr[16];
  int r = blockIdx.x, t = threadIdx.x;
  int f = flags[0];
  if (t < 9){
    float v = ld1f(x, (size_t)r*9 + t, f);
    if (t >= 3){
      int j = t - 3;
      size_t idx = (size_t)r*6 + j;
      int mf = flags[1];
      bool mm;
      if      (mf == 0) mm = ((const int*)mask)[idx] != 0;
      else if (mf == 1) mm = ((const unsigned char*)mask)[idx] != 0;
      else if (mf == 2) mm = ((const unsigned short*)mask)[idx] != 0;
      else              mm = ((const unsigned int*)mask)[idx] != 0;
      if (mm) v = ld1f(mval, j, f);
    }
    xr[t] = v;
  }
  __syncthreads();
  if (t < ENCD){
    float acc = ld1f(b, t, f);
    #pragma unroll
    for (int k = 0; k < 9; k++) acc = fmaf(xr[k], ld1f(w, (size_t)k*ENCD + t, f), acc);
    out[r*ENCD + t] = acc > 0.f ? acc : 0.01f*acc;
  } else {
    int j = t - ENCD;  // 0..19
    pef[(size_t)r*PED + j] = ld1f(pe, (size_t)r*PED + j, f);
  }
}
// merged encoder BN stats
__global__ void k_bn2x(const float* __restrict__ encb, const float* __restrict__ pef,
                       const void* __restrict__ eg, const void* __restrict__ eb,
                       const void* __restrict__ pg, const void* __restrict__ pb,
                       const int* __restrict__ dflag,
                       float* __restrict__ scE, float* __restrict__ shE,
                       float* __restrict__ scP, float* __restrict__ shP){
  int cb = blockIdx.x, t = threadIdx.x;
  const float* src; int ld, c; const void *g, *b; float *sc, *sh;
  if (cb < ENCD){ src = encb; ld = ENCD; c = cb; g = eg; b = eb; sc = scE; sh = shE; }
  else          { src = pef;  ld = PED;  c = cb - ENCD; g = pg; b = pb; sc = scP; sh = shP; }
  float s = 0.f, q = 0.f;
  for (int r = t; r < NN; r += 256){ float v = src[(size_t)r*ld + c]; s += v; q += v*v; }
  __shared__ float ss[256], qs[256];
  ss[t] = s; qs[t] = q; __syncthreads();
  for (int k = 128; k; k >>= 1){ if (t < k){ ss[t] += ss[t+k]; qs[t] += qs[t+k]; } __syncthreads(); }
  if (t == 0){
    int f = dflag[0];
    float mu  = ss[0] * (1.f/NN);
    float var = qs[0] * (1.f/NN) - mu*mu;
    float r1  = rsqrtf(var + BN_EPS);
    float scv = ld1f(g, c, f) * r1;
    sc[c] = scv; sh[c] = ld1f(b, c, f) - mu*scv;
  }
}
__global__ void k_concat(unsigned short* __restrict__ h, const float* __restrict__ encb,
                         const float* __restrict__ pef,
                         const float* __restrict__ scE, const float* __restrict__ shE,
                         const float* __restrict__ scP, const float* __restrict__ shP){
  int i = blockIdx.x*256 + threadIdx.x;
  int r = i >> 8, c = i & 255;
  float v;
  if (c < ENCD) v = encb[r*ENCD + c]*scE[c] + shE[c];
  else { int j = c - ENCD; v = pef[r*PED + j]*scP[j] + shP[j]; }
  h[i] = f2bs(v);
}

// ---------------- inline BN helpers ----------------
__device__ __forceinline__ void dualbn(const float* slab, int c, int f,
                                       const void* g1, size_t g1o,
                                       const void* g2, size_t g2o,
                                       const void* b2, size_t b2o,
                                       float& sc, float& sh){
  float mu  = slab[2*c] * (1.f/NN);
  float var = slab[2*c+1] * (1.f/NN) - mu*mu;
  float r1  = rsqrtf(var + BN_EPS);
  float gg  = ld1f(g1, g1o + c, f);
  float zv  = var * r1 * r1 * gg * gg;
  float r2  = rsqrtf(zv + BN_EPS);
  sc = r1 * gg * r2 * ld1f(g2, g2o + c, f);
  sh = ld1f(b2, b2o + c, f) - mu*sc;
}
__device__ __forceinline__ void singlebn(const float* slab, int c, int f,
                                         const void* g, size_t go,
                                         const void* b, size_t bo,
                                         float& sc, float& sh){
  float mu  = slab[2*c] * (1.f/NN);
  float var = slab[2*c+1] * (1.f/NN) - mu*mu;
  float r1  = rsqrtf(var + BN_EPS);
  sc = ld1f(g, go + c, f) * r1;
  sh = ld1f(b, bo + c, f) - mu*sc;
}

// ---------------- GINE gather (1-ahead CSR prefetch) ----------------
__device__ void dev_gather(const unsigned short* __restrict__ h0,
                           const float* __restrict__ t3, int hsrc,
                           const float* __restrict__ slabH,
                           const void* Hg1, size_t Hg1o, const void* Hg2, size_t Hg2o,
                           const void* Hb2, size_t Hb2o,
                           int dst, const int* __restrict__ rowstart,
                           const int* __restrict__ csr_src, const float2* __restrict__ csr_a,
                           const void* __restrict__ w, size_t woff,
                           const void* __restrict__ b, size_t boff, int f,
                           float* __restrict__ agg){
  int c = threadIdx.x;
  float sc = 1.f, sh = 0.f;
  if (hsrc) dualbn(slabH, c, f, Hg1, Hg1o, Hg2, Hg2o, Hb2, Hb2o, sc, sh);
  float w0 = ld1f(w, woff + c, f), w1 = ld1f(w, woff + HIDD + c, f);
  float bb = ld1f(b, boff + c, f);
  int beg = rowstart[dst], end = rowstart[dst + 1];
  float acc = 0.f;
  int sN = 0; float2 aN = make_float2(0.f, 0.f);
  if (beg < end){ sN = csr_src[beg]; aN = csr_a[beg]; }
  for (int i = beg; i < end; i++){
    int s = sN; float2 a = aN;
    if (i + 1 < end){ sN = csr_src[i + 1]; aN = csr_a[i + 1]; }
    float hv = hsrc ? t3[(size_t)s*HIDD + c]*sc + sh : bs2f(h0[(size_t)s*HIDD + c]);
    float m = hv + a.x*w0 + a.y*w1 + bb;
    acc += fmaxf(m, 0.f);
  }
  agg[(size_t)dst*HIDD + c] = acc;
}

// ---------------- MFMA GEMM device fn (in-place loads; r10 structure) -------
// APATH: 0 = A from (h0 bf16 | t3 f32*BN); 1 = GINE: H + agg;
//        2 = attn K-split combine (Opart, lsum) — plain sums;
//        3 = dual single-BN(t1,t2); 4 = decoder triple-BN fold.
// RESMODE: 0 none; 1 += H; 2 += BN1(t1)+BN2(t2).
template<int ACT, int APATH, int RESMODE, int OUTBF, int STATS>
__device__ void dev_mgemm(char* sm, int bn, int bm,
    const unsigned short* __restrict__ Ab, const float* __restrict__ Af, int hsrc,
    const float* __restrict__ agg,
    const float* __restrict__ Opart, const float* __restrict__ lsum,
    const float* __restrict__ t1p, const float* __restrict__ t2p,
    const float* __restrict__ slabH,
    const void* Hg1, size_t Hg1o, const void* Hg2, size_t Hg2o,
    const void* Hb2, size_t Hb2o,
    const void* Pg, size_t Pgo, const void* Pb, size_t Pbo,
    const float* __restrict__ slab1,
    const void* g1, size_t g1o, const void* b1, size_t b1o,
    const float* __restrict__ slab2,
    const void* g2, size_t g2o, const void* b2, size_t b2o,
    const unsigned short* __restrict__ Wt,
    const void* __restrict__ bias, size_t boff,
    void* __restrict__ C, int N_, int K, int qcols, float qscale,
    float* __restrict__ stats, int f){
  unsigned short (*As)[40] = (unsigned short(*)[40])sm;
  unsigned short (*Bs)[40] = (unsigned short(*)[40])(sm + 5120);
  constexpr bool NEEDH = (APATH <= 1 || RESMODE == 1 || APATH == 4);
  constexpr size_t TB = 10240 + (NEEDH ? 2048 : 0);
  float* scH = (float*)(sm + 10240); float* shH = scH + 256;
  float* tc1 = (float*)(sm + TB);    float* th1 = tc1 + 256;
  float* tc2 = th1 + 256;            float* th2 = tc2 + 256;
  int tid = threadIdx.x, L = tid & 63, wv = tid >> 6;
  int wm = wv >> 1, wn = wv & 1;
  int quad = L >> 4, lo = L & 15;
  int srow = tid >> 2, sk = (tid & 3)*8;

  if (NEEDH && (hsrc || APATH == 4)){
    int c = tid;
    float s, h;
    dualbn(slabH, c, f, Hg1, Hg1o, Hg2, Hg2o, Hb2, Hb2o, s, h);
    if (APATH == 4){
      float mu  = slabH[2*c] * (1.f/NN);
      float var = slabH[2*c+1] * (1.f/NN) - mu*mu;
      float muh = mu*s + h, varh = var*s*s;
      float rp  = rsqrtf(varh + BN_EPS);
      float sp  = ld1f(Pg, Pgo + c, f) * rp;
      float hp  = ld1f(Pb, Pbo + c, f) - muh*sp;
      s = s*sp; h = h*sp + hp;
    }
    scH[c] = s; shH[c] = h;
  }
  if (APATH == 3 || RESMODE == 2){
    int c = tid;
    float s, h;
    singlebn(slab1, c, f, g1, g1o, b1, b1o, s, h); tc1[c] = s; th1[c] = h;
    singlebn(slab2, c, f, g2, g2o, b2, b2o, s, h); tc2[c] = s; th2[c] = h;
  }
  __syncthreads();

  v4f acc[2][2];
  #pragma unroll
  for (int i = 0; i < 2; i++)
    #pragma unroll
    for (int j = 0; j < 2; j++) acc[i][j] = (v4f){0.f,0.f,0.f,0.f};

  for (int kk = 0; kk < K; kk += 32){
    int row = bm + srow, c0 = kk + sk;
    uint4 aval;
    if (APATH == 0 || APATH == 4){
      if (APATH == 0 && !hsrc){
        aval = *(const uint4*)(Ab + (size_t)row*K + c0);
      } else {
        unsigned short us8[8];
        #pragma unroll
        for (int j = 0; j < 8; j++){
          int c = c0 + j;
          us8[j] = f2bs(Af[(size_t)row*K + c]*scH[c] + shH[c]);
        }
        aval = *(const uint4*)us8;
      }
    } else if (APATH == 1){
      unsigned short us8[8];
      if (!hsrc){
        uint4 araw = *(const uint4*)(Ab + (size_t)row*K + c0);
        unsigned parts[4] = {araw.x, araw.y, araw.z, araw.w};
        #pragma unroll
        for (int p = 0; p < 4; p++){
          us8[2*p]   = f2bs(bs2f((unsigned short)(parts[p] & 0xffffu)) + agg[(size_t)row*K + c0 + 2*p]);
          us8[2*p+1] = f2bs(bs2f((unsigned short)(parts[p] >> 16))     + agg[(size_t)row*K + c0 + 2*p + 1]);
        }
      } else {
        #pragma unroll
        for (int j = 0; j < 8; j++){
          int c = c0 + j;
          us8[j] = f2bs(Af[(size_t)row*K + c]*scH[c] + shH[c] + agg[(size_t)row*K + c]);
        }
      }
      aval = *(const uint4*)us8;
    } else if (APATH == 2){
      int hd = c0 >> 5, d0 = c0 & 31;
      size_t mlb = ((size_t)row*8 + hd)*KSPLIT;
      float inv = 1.f / (lsum[mlb] + lsum[mlb+1] + lsum[mlb+2] + lsum[mlb+3]);
      const float* Op = Opart + mlb*32 + d0;
      unsigned short us8[8];
      #pragma unroll
      for (int j = 0; j < 8; j++){
        float v = (Op[j] + Op[32+j] + Op[64+j] + Op[96+j])*inv;
        us8[j] = f2bs(v);
      }
      aval = *(const uint4*)us8;
    } else { // APATH == 3
      unsigned short us8[8];
      #pragma unroll
      for (int j = 0; j < 8; j++){
        int c = c0 + j;
        float v = t1p[(size_t)row*HIDD + c]*tc1[c] + th1[c]
                + t2p[(size_t)row*HIDD + c]*tc2[c] + th2[c];
        us8[j] = f2bs(v);
      }
      aval = *(const uint4*)us8;
    }
    uint4 bval = *(const uint4*)(Wt + (size_t)(bn + srow)*K + c0);
    __syncthreads();
    *(uint4*)&As[srow][sk] = aval;
    *(uint4*)&Bs[srow][sk] = bval;
    __syncthreads();
    v8s af[2], bfr[2];
    af[0]  = *(const v8s*)&As[wm*32 + lo][quad*8];
    af[1]  = *(const v8s*)&As[wm*32 + 16 + lo][quad*8];
    bfr[0] = *(const v8s*)&Bs[wn*32 + lo][quad*8];
    bfr[1] = *(const v8s*)&Bs[wn*32 + 16 + lo][quad*8];
    #pragma unroll
    for (int mi = 0; mi < 2; mi++)
      #pragma unroll
      for (int nj = 0; nj < 2; nj++)
        acc[mi][nj] = __builtin_amdgcn_mfma_f32_16x16x32_bf16(af[mi], bfr[nj], acc[mi][nj], 0, 0, 0);
  }

  float ssum[2] = {0.f, 0.f}, ssq[2] = {0.f, 0.f};
  #pragma unroll
  for (int mi = 0; mi < 2; mi++){
    #pragma unroll
    for (int nj = 0; nj < 2; nj++){
      int col = bn + wn*32 + nj*16 + lo;
      float bv = ld1f(bias, boff + col, f);
      #pragma unroll
      for (int r = 0; r < 4; r++){
        int row = bm + wm*32 + mi*16 + quad*4 + r;
        float t = acc[mi][nj][r] + bv;
        if (ACT == 1) t = fmaxf(t, 0.f);
        if (ACT == 2) t = t > 0.f ? t : 0.01f*t;
        if (qcols && col < qcols) t *= qscale;
        if (RESMODE == 1)
          t += hsrc ? (Af[(size_t)row*N_ + col]*scH[col] + shH[col])
                    : bs2f(Ab[(size_t)row*N_ + col]);
        if (RESMODE == 2)
          t += t1p[(size_t)row*HIDD + col]*tc1[col] + th1[col]
             + t2p[(size_t)row*HIDD + col]*tc2[col] + th2[col];
        if (STATS){ ssum[nj] += t; ssq[nj] += t*t; }
        if (OUTBF) ((unsigned short*)C)[(size_t)row*N_ + col] = f2bs(t);
        else       ((float*)C)[(size_t)row*N_ + col] = t;
      }
    }
  }
  if (STATS){
    #pragma unroll
    for (int nj = 0; nj < 2; nj++){
      float s = ssum[nj], q = ssq[nj];
      s += __shfl_xor(s, 16, 64); s += __shfl_xor(s, 32, 64);
      q += __shfl_xor(q, 16, 64); q += __shfl_xor(q, 32, 64);
      if (quad == 0){
        int col = bn + wn*32 + nj*16 + lo;
        atomicAdd(&stats[2*col],   s);
        atomicAdd(&stats[2*col+1], q);
      }
    }
  }
}

// ---------------- MFMA flash attention: 512 threads, 128 q-rows/block -------
// no-max softmax in log2 domain; r10 staging structure (loads at loop head).
__launch_bounds__(512)
__global__ void k_d2(const unsigned short* __restrict__ qkv,
                     float* __restrict__ Opart, float* __restrict__ lsum){
  __shared__ unsigned short Ks[64][40];
  __shared__ unsigned short Vt[32][66];
  __shared__ unsigned short Ps[8][16][68];
  int b = blockIdx.x;
  int qt = b & 15, hd = (b >> 4) & 7, ks = b >> 7;
  int q0 = qt*128;
  int tid = threadIdx.x, L = tid & 63, wv = tid >> 6;   // wv 0..7
  int quad = L >> 4, lo = L & 15;
  int skey = tid >> 3, sd = (tid & 7)*4;

  v8s qf = *(const v8s*)(qkv + (size_t)(q0 + 16*wv + lo)*768 + hd*32 + quad*8);
  v4f o0 = (v4f){0.f,0.f,0.f,0.f}, o1 = (v4f){0.f,0.f,0.f,0.f};
  float lrow[4] = {0.f, 0.f, 0.f, 0.f};

  int kbeg = ks * (NN/KSPLIT), kend = kbeg + NN/KSPLIT;
  for (int kt = kbeg; kt < kend; kt += 64){
    const unsigned short* kp = qkv + (size_t)(kt + skey)*768 + 256 + hd*32 + sd;
    uint2 kraw = *(const uint2*)kp;
    uint2 vraw = *(const uint2*)(kp + 256);
    __syncthreads();                    // prev iter's Ks/Vt readers done
    *(uint2*)&Ks[skey][sd] = kraw;
    {
      unsigned short vs[4]; *(uint2*)vs = vraw;
      #pragma unroll
      for (int j = 0; j < 4; j++) Vt[sd + j][skey] = vs[j];
    }
    __syncthreads();
    v4f s[4];
    #pragma unroll
    for (int sub = 0; sub < 4; sub++){
      v8s kf = *(const v8s*)&Ks[sub*16 + lo][quad*8];
      s[sub] = __builtin_amdgcn_mfma_f32_16x16x32_bf16(qf, kf, (v4f){0.f,0.f,0.f,0.f}, 0, 0, 0);
    }
    #pragma unroll
    for (int r = 0; r < 4; r++){
      #pragma unroll
      for (int sub = 0; sub < 4; sub++){
        float p = exp2f(s[sub][r]);
        Ps[wv][quad*4 + r][sub*16 + lo] = f2bs(p);
        lrow[r] += p;
      }
    }
    // Ps is wave-private: no block barrier needed before PV
    #pragma unroll
    for (int kc = 0; kc < 2; kc++){
      v8s pf  = *(const v8s*)&Ps[wv][lo][kc*32 + quad*8];
      v8s v0f = *(const v8s*)&Vt[lo][kc*32 + quad*8];
      v8s v1f = *(const v8s*)&Vt[16 + lo][kc*32 + quad*8];
      o0 = __builtin_amdgcn_mfma_f32_16x16x32_bf16(pf, v0f, o0, 0, 0, 0);
      o1 = __builtin_amdgcn_mfma_f32_16x16x32_bf16(pf, v1f, o1, 0, 0, 0);
    }
  }
  #pragma unroll
  for (int r = 0; r < 4; r++){
    float v = lrow[r];
    #pragma unroll
    for (int off = 1; off < 16; off <<= 1) v += __shfl_xor(v, off, 64);
    lrow[r] = v;
  }
  #pragma unroll
  for (int r = 0; r < 4; r++){
    int row = q0 + 16*wv + quad*4 + r;
    size_t base = (((size_t)row*8 + hd)*KSPLIT + ks)*32;
    Opart[base + lo]      = o0[r];
    Opart[base + 16 + lo] = o1[r];
    if (lo == 0) lsum[((size_t)row*8 + hd)*KSPLIT + ks] = lrow[r];
  }
}

// ---------------- fat dispatch 1: QKV GEMM (384) + gather (2048) ----------
__launch_bounds__(256)
__global__ void k_d1(const unsigned short* __restrict__ h0, const float* __restrict__ t3,
                     int hsrc, const float* __restrict__ slabH,
                     const void* Hg1, size_t Hg1o, const void* Hg2, size_t Hg2o,
                     const void* Hb2, size_t Hb2o,
                     const unsigned short* __restrict__ qkw,
                     const void* qb, size_t qbo, unsigned short* __restrict__ qkvb,
                     const int* __restrict__ rowstart, const int* __restrict__ csr_src,
                     const float2* __restrict__ csr_a,
                     const void* gw, size_t gwo, const void* gb, size_t gbo,
                     float* __restrict__ agg, const int* __restrict__ dflagp){
  __shared__ char sm[12288];
  int f = dflagp[0];
  int bx = blockIdx.x;
  if (bx < 384){
    dev_mgemm<0,0,0,1,0>(sm, (bx % 12)*64, (bx / 12)*64, h0, t3, hsrc,
        nullptr, nullptr, nullptr, nullptr, nullptr,
        slabH, Hg1, Hg1o, Hg2, Hg2o, Hb2, Hb2o, nullptr, 0, nullptr, 0,
        nullptr, nullptr, 0, nullptr, 0, nullptr, nullptr, 0, nullptr, 0,
        qkw, qb, qbo, qkvb, 768, 256, 256, ATT_SCALE_L2E, nullptr, f);
  } else {
    dev_gather(h0, t3, hsrc, slabH, Hg1, Hg1o, Hg2, Hg2o, Hb2, Hb2o,
               bx - 384, rowstart, csr_src, csr_a, gw, gwo, gb, gbo, f, agg);
  }
}

// ---------------- fat dispatch 3: GINE GEMM (128) + attn-out GEMM (128) ----
// NOTE: t2 must NOT alias agg — gine branch reads agg while attnout writes t2.
__launch_bounds__(256)
__global__ void k_g3(const unsigned short* __restrict__ h0, const float* __restrict__ t3,
                     int hsrc, const float* __restrict__ slabH,
                     const void* Hg1, size_t Hg1o, const void* Hg2, size_t Hg2o,
                     const void* Hb2, size_t Hb2o,
                     const float* __restrict__ agg,
                     const unsigned short* __restrict__ gmw,
                     const void* gmb, size_t gmbo,
                     float* __restrict__ t1, float* __restrict__ stats1,
                     const float* __restrict__ Opart, const float* __restrict__ lsum,
                     const unsigned short* __restrict__ aow,
                     const void* aob, size_t aobo,
                     float* __restrict__ t2, float* __restrict__ stats2,
                     const int* __restrict__ dflagp){
  __shared__ char sm[12288];
  int f = dflagp[0];
  int bx = blockIdx.x;
  if (bx < 128){
    dev_mgemm<2,1,1,0,1>(sm, (bx & 3)*64, (bx >> 2)*64, h0, t3, hsrc,
        agg, nullptr, nullptr, nullptr, nullptr,
        slabH, Hg1, Hg1o, Hg2, Hg2o, Hb2, Hb2o, nullptr, 0, nullptr, 0,
        nullptr, nullptr, 0, nullptr, 0, nullptr, nullptr, 0, nullptr, 0,
        gmw, gmb, gmbo, t1, 256, 256, 0, 1.f, stats1, f);
  } else {
    int bb = bx - 128;
    dev_mgemm<0,2,1,0,1>(sm, (bb & 3)*64, (bb >> 2)*64, h0, t3, hsrc,
        nullptr, Opart, lsum, nullptr, nullptr,
        slabH, Hg1, Hg1o, Hg2, Hg2o, Hb2, Hb2o, nullptr, 0, nullptr, 0,
        nullptr, nullptr, 0, nullptr, 0, nullptr, nullptr, 0, nullptr, 0,
        aow, aob, aobo, t2, 256, 256, 0, 1.f, stats2, f);
  }
}

// ---------------- mlp1 GEMM ----------------
__launch_bounds__(256)
__global__ void k_g4(const float* __restrict__ t1, const float* __restrict__ t2,
                     const float* __restrict__ slab1,
                     const void* g1, size_t g1o, const void* b1, size_t b1o,
                     const float* __restrict__ slab2,
                     const void* g2, size_t g2o, const void* b2, size_t b2o,
                     const unsigned short* __restrict__ m1w,
                     const void* m1b, size_t m1bo,
                     unsigned short* __restrict__ u, const int* __restrict__ dflagp){
  __shared__ char sm[14336];
  dev_mgemm<1,3,0,1,0>(sm, blockIdx.x*64, blockIdx.y*64, nullptr, nullptr, 0,
      nullptr, nullptr, nullptr, t1, t2,
      nullptr, nullptr, 0, nullptr, 0, nullptr, 0, nullptr, 0, nullptr, 0,
      slab1, g1, g1o, b1, b1o, slab2, g2, g2o, b2, b2o,
      m1w, m1b, m1bo, u, 512, 256, 0, 1.f, nullptr, dflagp[0]);
}

// ---------------- mlp2 GEMM ----------------
__launch_bounds__(256)
__global__ void k_g5(const unsigned short* __restrict__ u,
                     const float* __restrict__ t1, const float* __restrict__ t2,
                     const float* __restrict__ slab1,
                     const void* g1, size_t g1o, const void* b1, size_t b1o,
                     const float* __restrict__ slab2,
                     const void* g2, size_t g2o, const void* b2, size_t b2o,
                     const unsigned short* __restrict__ m2w,
                     const void* m2b, size_t m2bo,
                     float* __restrict__ t3, float* __restrict__ stats3,
                     const int* __restrict__ dflagp){
  __shared__ char sm[14336];
  dev_mgemm<0,0,2,0,1>(sm, blockIdx.x*64, blockIdx.y*64, u, nullptr, 0,
      nullptr, nullptr, nullptr, t1, t2,
      nullptr, nullptr, 0, nullptr, 0, nullptr, 0, nullptr, 0, nullptr, 0,
      slab1, g1, g1o, b1, b1o, slab2, g2, g2o, b2, b2o,
      m2w, m2b, m2bo, t3, 256, 512, 0, 1.f, stats3, dflagp[0]);
}

// ---------------- decoder stage 1 GEMM ----------------
__launch_bounds__(256)
__global__ void k_gdec(const float* __restrict__ t3, const float* __restrict__ slabH,
                       const void* Hg1, size_t Hg1o, const void* Hg2, size_t Hg2o,
                       const void* Hb2, size_t Hb2o,
                       const void* Pg, const void* Pb,
                       const unsigned short* __restrict__ d1w,
                       const void* d1bv, unsigned short* __restrict__ d1b,
                       const int* __restrict__ dflagp){
  __shared__ char sm[12288];
  dev_mgemm<2,4,0,1,0>(sm, blockIdx.x*64, blockIdx.y*64, nullptr, t3, 1,
      nullptr, nullptr, nullptr, nullptr, nullptr,
      slabH, Hg1, Hg1o, Hg2, Hg2o, Hb2, Hb2o, Pg, 0, Pb, 0,
      nullptr, nullptr, 0, nullptr, 0, nullptr, nullptr, 0, nullptr, 0,
      d1w, d1bv, 0, d1b, 256, 256, 0, 1.f, nullptr, dflagp[0]);
}

// ---------------- decoder stage 2 ----------------
__global__ void k_dec2(const unsigned short* __restrict__ d1, const void* __restrict__ w,
                       const void* __restrict__ b, const int* __restrict__ dflag,
                       void* __restrict__ out){
  int r = blockIdx.x, t = threadIdx.x;
  int f = dflag[0];
  float a = bs2f(d1[(size_t)r*HIDD + t]);
  float p[6];
  #pragma unroll
  for (int n = 0; n < 6; n++) p[n] = a * ld1f(w, (size_t)t*6 + n, f);
  #pragma unroll
  for (int off = 32; off >= 1; off >>= 1)
    #pragma unroll
    for (int n = 0; n < 6; n++) p[n] += __shfl_down(p[n], off, 64);
  __shared__ float red[4][6];
  int wvv = t >> 6, ln = t & 63;
  if (ln == 0)
    #pragma unroll
    for (int n = 0; n < 6; n++) red[wvv][n] = p[n];
  __syncthreads();
  if (t < 6){
    float s = red[0][t] + red[1][t] + red[2][t] + red[3][t] + ld1f(b, t, f);
    if (f) ((bf16*)out)[r*6 + t] = __float2bfloat16(s);
    else   ((float*)out)[r*6 + t] = s;
  }
}

extern "C" void kernel_launch(void* const* d_in, const int* in_sizes, int n_in,
                              void* d_out, int out_size, void* d_ws, size_t ws_size,
                              hipStream_t stream){
  const void* x          = d_in[0];
  const void* pe         = d_in[1];
  const void* edge_attr  = d_in[2];
  const void* mask_value = d_in[3];
  const void* enc_w = d_in[4];  const void* enc_b = d_in[5];
  const void* in_g  = d_in[6];  const void* in_b  = d_in[7];
  const void* pe_g  = d_in[8];  const void* pe_b  = d_in[9];
  const void* gine_ew = d_in[10]; const void* gine_eb = d_in[11];
  const void* gine_mw = d_in[12]; const void* gine_mb = d_in[13];
  const void* attn_inw  = d_in[14]; const void* attn_inb  = d_in[15];
  const void* attn_outw = d_in[16]; const void* attn_outb = d_in[17];
  const void* mlp1w = d_in[18]; const void* mlp1b = d_in[19];
  const void* mlp2w = d_in[20]; const void* mlp2b = d_in[21];
  const void* n1g = d_in[22]; const void* n1b = d_in[23];
  const void* n2g = d_in[24]; const void* n2b = d_in[25];
  const void* n3g = d_in[26]; const void* n3b = d_in[27];
  const void* obn_g = d_in[28]; const void* obn_b = d_in[29];
  const void* pd_g  = d_in[30]; const void* pd_b  = d_in[31];
  const void* dec1w = d_in[32]; const void* dec1b = d_in[33];
  const void* dec2w = d_in[34]; const void* dec2b = d_in[35];
  const int*  edge_index = (const int*)d_in[36];
  const void* mask = d_in[37];
  (void)in_sizes; (void)n_in; (void)out_size; (void)ws_size;

  char* cur = (char*)d_ws;
  auto alloc = [&](size_t bytes)->char*{
    char* p = cur; cur += (bytes + 63) & ~(size_t)63; return p;
  };
  int*   flags = (int*)alloc(64);
  int*   dflag = flags;
  float* scE = (float*)alloc(ENCD*4); float* shE = (float*)alloc(ENCD*4);
  float* scP = (float*)alloc(PED*4);  float* shP = (float*)alloc(PED*4);
  int*   counts = (int*)alloc(2048*4);
  float* stats1 = (float*)alloc((size_t)LLAYERS*512*4);
  float* stats2 = (float*)alloc((size_t)LLAYERS*512*4);
  float* stats3 = (float*)alloc((size_t)LLAYERS*512*4);
  size_t zero_bytes = 2048*4 + 3*(size_t)LLAYERS*512*4;
  int*    rowstart = (int*)alloc(2052*4);
  int*    cursor   = (int*)alloc(2048*4);
  int*    csr_src  = (int*)alloc((size_t)EE*4);
  float2* csr_a    = (float2*)alloc((size_t)EE*8);
  unsigned short* h    = (unsigned short*)alloc((size_t)NN*HIDD*2);   // layer-0 only
  float*          t1   = (float*)alloc((size_t)NN*HIDD*4);
  float*          agg  = (float*)alloc((size_t)NN*HIDD*4);
  float*          t2   = (float*)alloc((size_t)NN*HIDD*4);   // DEDICATED (no agg alias!)
  float*          t3   = (float*)alloc((size_t)NN*HIDD*4);
  unsigned short* qkvb = (unsigned short*)alloc((size_t)NN*768*2);    // alias u, encb+pef
  float*          Opart= (float*)alloc((size_t)NN*8*KSPLIT*32*4);     // 8 MB; alias d1b
  float*          lsum = (float*)alloc((size_t)NN*8*KSPLIT*4);
  unsigned short* sqw  = (unsigned short*)alloc((size_t)17*65536*2);
  unsigned short* ainw_t = (unsigned short*)alloc((size_t)8*768*256*2);
  unsigned short* m1w_t  = (unsigned short*)alloc((size_t)8*512*256*2);
  unsigned short* m2w_t  = (unsigned short*)alloc((size_t)8*256*512*2);
  unsigned short* gmw_t   = sqw;
  unsigned short* aoutw_t = sqw + (size_t)8*65536;
  unsigned short* d1w_t   = sqw + (size_t)16*65536;
  unsigned short* u    = qkvb;
  float*          encb = (float*)qkvb;
  float*          pef  = (float*)qkvb + (size_t)NN*ENCD;
  unsigned short* d1b  = (unsigned short*)Opart;

  // ---- detection, CSR, transposes, encoder ----
  k_detect2<<<2, 256, 0, stream>>>((const unsigned int*)x, (const unsigned char*)mask, flags);
  hipMemsetAsync(counts, 0, zero_bytes, stream);
  k_csr_count<<<EE/256, 256, 0, stream>>>(edge_index, counts);
  k_csr_scan<<<1, 256, 0, stream>>>(counts, rowstart, cursor);
  k_csr_fill<<<EE/256, 256, 0, stream>>>(edge_index, edge_attr, dflag, cursor, csr_src, csr_a);
  k_tw3<<<dim3(8, 8, 17), 256, 0, stream>>>(gine_mw, attn_outw, dec1w, sqw, dflag);
  k_tw<<<dim3(24, 8, 8), 256, 0, stream>>>(attn_inw, ainw_t, 256, 768, dflag);
  k_tw<<<dim3(16, 8, 8), 256, 0, stream>>>(mlp1w,    m1w_t,  256, 512, dflag);
  k_tw<<<dim3(8, 16, 8), 256, 0, stream>>>(mlp2w,    m2w_t,  512, 256, dflag);
  k_encode<<<NN, 256, 0, stream>>>(x, mask_value, mask, flags, enc_w, enc_b, pe, encb, pef);
  k_bn2x<<<256, 256, 0, stream>>>(encb, pef, in_g, in_b, pe_g, pe_b, dflag, scE, shE, scP, shP);
  k_concat<<<NN*HIDD/256, 256, 0, stream>>>(h, encb, pef, scE, shE, scP, shP);

  for (int l = 0; l < LLAYERS; l++){
    int hs = (l > 0);
    const float* slH = stats3 + (size_t)(hs ? (l-1) : 0)*512;
    size_t o3 = (size_t)(hs ? (l-1) : 0)*256;
    k_d1<<<2432, 256, 0, stream>>>(h, t3, hs, slH, n3g, o3, obn_g, o3, obn_b, o3,
        ainw_t + (size_t)l*196608, attn_inb, (size_t)l*768, qkvb,
        rowstart, csr_src, csr_a,
        gine_ew, (size_t)l*2*HIDD, gine_eb, (size_t)l*HIDD, agg, dflag);
    k_d2<<<512, 512, 0, stream>>>(qkvb, Opart, lsum);
    k_g3<<<256, 256, 0, stream>>>(h, t3, hs, slH, n3g, o3, obn_g, o3, obn_b, o3,
        agg, gmw_t + (size_t)l*65536, gine_mb, (size_t)l*256, t1, stats1 + (size_t)l*512,
        Opart, lsum, aoutw_t + (size_t)l*65536, attn_outb, (size_t)l*256,
        t2, stats2 + (size_t)l*512, dflag);
    k_g4<<<dim3(8,32), 256, 0, stream>>>(t1, t2,
        stats1 + (size_t)l*512, n1g, (size_t)l*256, n1b, (size_t)l*256,
        stats2 + (size_t)l*512, n2g, (size_t)l*256, n2b, (size_t)l*256,
        m1w_t + (size_t)l*131072, mlp1b, (size_t)l*512, u, dflag);
    k_g5<<<dim3(4,32), 256, 0, stream>>>(u, t1, t2,
        stats1 + (size_t)l*512, n1g, (size_t)l*256, n1b, (size_t)l*256,
        stats2 + (size_t)l*512, n2g, (size_t)l*256, n2b, (size_t)l*256,
        m2w_t + (size_t)l*131072, mlp2b, (size_t)l*256, t3, stats3 + (size_t)l*512, dflag);
  }

  // ---- decoder ----
  k_gdec<<<dim3(4,32), 256, 0, stream>>>(t3, stats3 + (size_t)7*512,
      n3g, (size_t)7*256, obn_g, (size_t)7*256, obn_b, (size_t)7*256,
      pd_g, pd_b, d1w_t, dec1b, d1b, dflag);
  k_dec2<<<NN, 256, 0, stream>>>(d1b, dec2w, dec2b, dflag, d_out);
}